// Round 4
// baseline (497.001 us; speedup 1.0000x reference)
//
#include <hip/hip_runtime.h>

#define BB 128
#define TT 2048
#define II 32
#define HH 64

// ws layout: float xh[2][BB][HH][TT]   (xw written by proj, overwritten in-place by h in rnn)
// total = 2*128*64*2048*4 = 128 MiB

__global__ __launch_bounds__(256) void proj_kernel(
    const float* __restrict__ x,
    const float* __restrict__ Wf, const float* __restrict__ bihf, const float* __restrict__ bhhf,
    const float* __restrict__ Wb, const float* __restrict__ bihb, const float* __restrict__ bhhb,
    float* __restrict__ xh)
{
    const int lane = threadIdx.x & 63;
    const int wv = __builtin_amdgcn_readfirstlane(threadIdx.x >> 6);
    const int blk = blockIdx.x;          // 0..4095
    const int b = blk >> 5;
    const int t = ((blk & 31) << 6) + lane;

    float xr[II];
    {
        const float4* xp = (const float4*)(x + ((size_t)b * TT + t) * II);
        #pragma unroll
        for (int k4 = 0; k4 < II / 4; ++k4) {
            float4 v = xp[k4];
            xr[4*k4+0] = v.x; xr[4*k4+1] = v.y; xr[4*k4+2] = v.z; xr[4*k4+3] = v.w;
        }
    }
    float* outF = xh + (size_t)b * HH * TT + t;
    float* outB = xh + (size_t)(BB + b) * HH * TT + t;
    #pragma unroll 4
    for (int ii = 0; ii < 16; ++ii) {
        const int i = wv * 16 + ii;                    // wave-uniform -> scalar W loads
        const float* wfr = Wf + i * II;
        const float* wbr = Wb + i * II;
        float af0 = bihf[i] + bhhf[i], af1 = 0.f;
        float ab0 = bihb[i] + bhhb[i], ab1 = 0.f;
        #pragma unroll
        for (int k = 0; k < II; k += 2) {
            af0 = fmaf(wfr[k],   xr[k],   af0);
            af1 = fmaf(wfr[k+1], xr[k+1], af1);
            ab0 = fmaf(wbr[k],   xr[k],   ab0);
            ab1 = fmaf(wbr[k+1], xr[k+1], ab1);
        }
        outF[(size_t)i * TT] = af0 + af1;   // coalesced 256B store
        outB[(size_t)i * TT] = ab0 + ab1;
    }
}

// ---------------- general-W fallback (serial chain), R2-proven ----------------
#define RNN_STEP(XOV, HQ, CURBUF, NXTBUF) {                                   \
    float a0 = (XOV), a1 = 0.f, a2 = 0.f, a3 = 0.f;                           \
    const float* hs = hsh[CURBUF];                                            \
    _Pragma("unroll")                                                         \
    for (int j4 = 0; j4 < HH / 4; ++j4) {                                     \
        float4 h4 = *(const float4*)(hs + 4 * j4);  /* ds_read_b128 bcast */  \
        a0 = fmaf(w[4*j4+0], h4.x, a0);                                       \
        a1 = fmaf(w[4*j4+1], h4.y, a1);                                       \
        a2 = fmaf(w[4*j4+2], h4.z, a2);                                       \
        a3 = fmaf(w[4*j4+3], h4.w, a3);                                       \
    }                                                                         \
    HQ = fmaxf((a0 + a1) + (a2 + a3), 0.0f);                                  \
    hsh[NXTBUF][lane] = HQ;                                                   \
}

template<int DIR>
__device__ __noinline__ void rnn_serial(const float* __restrict__ W,
                                        float* __restrict__ xh,
                                        int b, int lane)
{
    float w[HH];
    {
        const float4* wp = (const float4*)(W + lane * HH);
        #pragma unroll
        for (int j4 = 0; j4 < HH / 4; ++j4) {
            float4 v = wp[j4];
            w[4*j4+0] = v.x; w[4*j4+1] = v.y; w[4*j4+2] = v.z; w[4*j4+3] = v.w;
        }
    }
    float* base = xh + ((size_t)(DIR * BB + b) * HH + lane) * TT;

    __shared__ __align__(16) float hsh[2][HH];
    hsh[0][lane] = 0.0f;
    __syncthreads();

    constexpr int STEP = DIR ? -4 : 4;
    int gbase = DIR ? (TT - 4) : 0;
    float4 xq = *(const float4*)(base + gbase);

    for (int g = 0; g < TT / 4; ++g) {
        const int gnext = (g + 1 < TT / 4) ? (gbase + STEP) : gbase;
        const float4 xn = *(const float4*)(base + gnext);

        float hq0, hq1, hq2, hq3;
        if (DIR == 0) {
            RNN_STEP(xq.x, hq0, 0, 1)
            RNN_STEP(xq.y, hq1, 1, 0)
            RNN_STEP(xq.z, hq2, 0, 1)
            RNN_STEP(xq.w, hq3, 1, 0)
        } else {
            RNN_STEP(xq.w, hq0, 0, 1)
            RNN_STEP(xq.z, hq1, 1, 0)
            RNN_STEP(xq.y, hq2, 0, 1)
            RNN_STEP(xq.x, hq3, 1, 0)
        }

        float4 st;
        if (DIR == 0) { st.x = hq0; st.y = hq1; st.z = hq2; st.w = hq3; }
        else          { st.x = hq3; st.y = hq2; st.z = hq1; st.w = hq0; }
        *(float4*)(base + gbase) = st;

        gbase = gnext;
        xq = xn;
    }
}

// ---------------- rnn: identity fast-path (parallel scan) + fallback ----------
// h_t = max(h_{t-1} + a_t, 0) is f(h)=max(h+a,b) with b=0; composition
// (A,B) then (A',B') = (A+A', max(B+A', B')) is associative -> prefix scan.
__global__ __launch_bounds__(64) void rnn_kernel(
    const float* __restrict__ Whf, const float* __restrict__ Whb,
    float* __restrict__ xh)
{
    const int lane = threadIdx.x;
    const int row  = blockIdx.x;         // 0..16383
    const int dir  = row >> 13;
    const int rid  = row & 8191;
    const int b    = rid >> 6;
    const int hrow = rid & 63;
    const float* W = dir ? Whb : Whf;

    // load W row `lane` and test identity (wave-uniform verdict)
    bool ok = true;
    {
        const float4* wp = (const float4*)(W + lane * HH);
        #pragma unroll
        for (int j4 = 0; j4 < HH / 4; ++j4) {
            float4 v = wp[j4];
            ok &= (v.x == ((4*j4+0 == lane) ? 1.0f : 0.0f));
            ok &= (v.y == ((4*j4+1 == lane) ? 1.0f : 0.0f));
            ok &= (v.z == ((4*j4+2 == lane) ? 1.0f : 0.0f));
            ok &= (v.w == ((4*j4+3 == lane) ? 1.0f : 0.0f));
        }
    }
    const bool isI = (__ballot(ok) == ~0ull);

    if (!isI) {
        if (hrow != 0) return;
        if (dir == 0) rnn_serial<0>(Whf, xh, b, lane);
        else          rnn_serial<1>(Whb, xh, b, lane);
        return;
    }

    float* base = xh + ((size_t)(dir * BB + b) * HH + hrow) * TT;

    // gather this lane's 32 elements in TIME order (dir=1: memory-reversed)
    float a[32];
    if (dir == 0) {
        const float4* xp = (const float4*)(base + lane * 32);
        #pragma unroll
        for (int q = 0; q < 8; ++q) {
            float4 v = xp[q];
            a[4*q+0] = v.x; a[4*q+1] = v.y; a[4*q+2] = v.z; a[4*q+3] = v.w;
        }
    } else {
        const float4* xp = (const float4*)(base + (TT - 32 - lane * 32));
        #pragma unroll
        for (int q = 0; q < 8; ++q) {
            float4 v = xp[q];
            a[31-4*q] = v.x; a[30-4*q] = v.y; a[29-4*q] = v.z; a[28-4*q] = v.w;
        }
    }

    // in-lane compose over 32 elems: (A,B) with identity (0, -inf)
    float A = 0.0f, Bv = -__builtin_inff();
    #pragma unroll
    for (int j = 0; j < 32; ++j) {
        A  = A + a[j];
        Bv = fmaxf(Bv + a[j], 0.0f);
    }

    // inclusive wave scan over lanes
    #pragma unroll
    for (int off = 1; off < 64; off <<= 1) {
        float Au = __shfl_up(A,  (unsigned)off);
        float Bu = __shfl_up(Bv, (unsigned)off);
        if (lane >= off) {
            Bv = fmaxf(Bu + A, Bv);   // uses pre-update A (current segment's A)
            A  = Au + A;
        }
    }

    // carry-in = exclusive prefix applied to h_init = 0
    float Ae = __shfl_up(A, 1u);
    float Be = __shfl_up(Bv, 1u);
    float h = (lane == 0) ? 0.0f : fmaxf(Ae, Be);

    // apply sequentially within the lane (exact within-segment arithmetic)
    #pragma unroll
    for (int j = 0; j < 32; ++j) {
        h = fmaxf(h + a[j], 0.0f);
        a[j] = h;
    }

    // store back in memory order
    if (dir == 0) {
        float4* op = (float4*)(base + lane * 32);
        #pragma unroll
        for (int q = 0; q < 8; ++q) {
            float4 st; st.x = a[4*q+0]; st.y = a[4*q+1]; st.z = a[4*q+2]; st.w = a[4*q+3];
            op[q] = st;
        }
    } else {
        float4* op = (float4*)(base + (TT - 32 - lane * 32));
        #pragma unroll
        for (int q = 0; q < 8; ++q) {
            float4 st; st.x = a[31-4*q]; st.y = a[30-4*q]; st.z = a[29-4*q]; st.w = a[28-4*q];
            op[q] = st;
        }
    }
}

// lanes = t. h-row (128 floats) in VGPRs per lane; ff0 rows are wave-uniform
// -> scalar loads as SGPR FMA operands. No LDS, no reductions, per-lane output.
// __launch_bounds__(256, 2): min 2 waves/EU -> VGPR cap 256, so hr[128]+temps
// (~150 VGPRs) stay register-resident. Default heuristic capped at 88 VGPRs
// and spilled hr to scratch -> 6x slowdown (R3: 332 us, VALUBusy 22%).
__global__ __launch_bounds__(256, 2) void mlp_kernel(
    const float* __restrict__ xh,
    const float* __restrict__ w0, const float* __restrict__ b0,
    const float* __restrict__ w1, const float* __restrict__ b1,
    float* __restrict__ out)
{
    const int lane = threadIdx.x & 63;
    const int tile = __builtin_amdgcn_readfirstlane(blockIdx.x * 4 + (threadIdx.x >> 6));
    const int b = tile >> 5;
    const int t = ((tile & 31) << 6) + lane;

    float hr[2 * HH];
    {
        const float* pf = xh + (size_t)b * HH * TT + t;
        const float* pb = xh + (size_t)(BB + b) * HH * TT + t;
        #pragma unroll
        for (int j = 0; j < HH; ++j) {
            hr[j]      = pf[(size_t)j * TT];   // coalesced 256B per j
            hr[HH + j] = pb[(size_t)j * TT];
        }
    }

    float oa = 0.0f;
    #pragma unroll 2
    for (int k = 0; k < 2 * HH; ++k) {
        const float* wr = w0 + k * (2 * HH);   // wave-uniform row -> s_loads
        float a0 = b0[k], a1 = 0.f, a2 = 0.f, a3 = 0.f;
        #pragma unroll
        for (int j4 = 0; j4 < (2 * HH) / 4; ++j4) {
            a0 = fmaf(wr[4*j4+0], hr[4*j4+0], a0);
            a1 = fmaf(wr[4*j4+1], hr[4*j4+1], a1);
            a2 = fmaf(wr[4*j4+2], hr[4*j4+2], a2);
            a3 = fmaf(wr[4*j4+3], hr[4*j4+3], a3);
        }
        float v = (a0 + a1) + (a2 + a3);
        v = fmaxf(v, 0.01f * v);               // leaky_relu, slope 0.01
        oa = fmaf(v, w1[k], oa);
    }
    out[(size_t)b * TT + t] = oa + b1[0];
}

extern "C" void kernel_launch(void* const* d_in, const int* in_sizes, int n_in,
                              void* d_out, int out_size, void* d_ws, size_t ws_size,
                              hipStream_t stream) {
    (void)in_sizes; (void)n_in; (void)out_size; (void)ws_size;
    const float* x    = (const float*)d_in[0];
    const float* Wihf = (const float*)d_in[1];
    const float* Whhf = (const float*)d_in[2];
    const float* bihf = (const float*)d_in[3];
    const float* bhhf = (const float*)d_in[4];
    const float* Wihb = (const float*)d_in[5];
    const float* Whhb = (const float*)d_in[6];
    const float* bihb = (const float*)d_in[7];
    const float* bhhb = (const float*)d_in[8];
    const float* ff0w = (const float*)d_in[9];
    const float* ff0b = (const float*)d_in[10];
    const float* ff1w = (const float*)d_in[11];
    const float* ff1b = (const float*)d_in[12];
    float* xh = (float*)d_ws;

    proj_kernel<<<dim3(BB * (TT / 64)), dim3(256), 0, stream>>>(
        x, Wihf, bihf, bhhf, Wihb, bihb, bhhb, xh);
    rnn_kernel<<<dim3(2 * BB * HH), dim3(64), 0, stream>>>(Whhf, Whhb, xh);
    mlp_kernel<<<dim3(BB * (TT / 64) / 4), dim3(256), 0, stream>>>(
        xh, ff0w, ff0b, ff1w, ff1b, (float*)d_out);
}

// Round 5
// 384.520 us; speedup vs baseline: 1.2925x; 1.2925x over previous
//
#include <hip/hip_runtime.h>

#define BB 128
#define TT 2048
#define II 32
#define HH 64

// ws layout: float xh[2][BB][HH][TT]   (xw written by proj, overwritten in-place by h in rnn)
// total = 2*128*64*2048*4 = 128 MiB

__global__ __launch_bounds__(256) void proj_kernel(
    const float* __restrict__ x,
    const float* __restrict__ Wf, const float* __restrict__ bihf, const float* __restrict__ bhhf,
    const float* __restrict__ Wb, const float* __restrict__ bihb, const float* __restrict__ bhhb,
    float* __restrict__ xh)
{
    const int lane = threadIdx.x & 63;
    const int wv = __builtin_amdgcn_readfirstlane(threadIdx.x >> 6);
    const int blk = blockIdx.x;          // 0..4095
    const int b = blk >> 5;
    const int t = ((blk & 31) << 6) + lane;

    float xr[II];
    {
        const float4* xp = (const float4*)(x + ((size_t)b * TT + t) * II);
        #pragma unroll
        for (int k4 = 0; k4 < II / 4; ++k4) {
            float4 v = xp[k4];
            xr[4*k4+0] = v.x; xr[4*k4+1] = v.y; xr[4*k4+2] = v.z; xr[4*k4+3] = v.w;
        }
    }
    float* outF = xh + (size_t)b * HH * TT + t;
    float* outB = xh + (size_t)(BB + b) * HH * TT + t;
    #pragma unroll 4
    for (int ii = 0; ii < 16; ++ii) {
        const int i = wv * 16 + ii;                    // wave-uniform -> scalar W loads
        const float* wfr = Wf + i * II;
        const float* wbr = Wb + i * II;
        float af0 = bihf[i] + bhhf[i], af1 = 0.f;
        float ab0 = bihb[i] + bhhb[i], ab1 = 0.f;
        #pragma unroll
        for (int k = 0; k < II; k += 2) {
            af0 = fmaf(wfr[k],   xr[k],   af0);
            af1 = fmaf(wfr[k+1], xr[k+1], af1);
            ab0 = fmaf(wbr[k],   xr[k],   ab0);
            ab1 = fmaf(wbr[k+1], xr[k+1], ab1);
        }
        outF[(size_t)i * TT] = af0 + af1;   // coalesced 256B store
        outB[(size_t)i * TT] = ab0 + ab1;
    }
}

// ---------------- general-W fallback (serial chain), R2-proven ----------------
#define RNN_STEP(XOV, HQ, CURBUF, NXTBUF) {                                   \
    float a0 = (XOV), a1 = 0.f, a2 = 0.f, a3 = 0.f;                           \
    const float* hs = hsh[CURBUF];                                            \
    _Pragma("unroll")                                                         \
    for (int j4 = 0; j4 < HH / 4; ++j4) {                                     \
        float4 h4 = *(const float4*)(hs + 4 * j4);  /* ds_read_b128 bcast */  \
        a0 = fmaf(w[4*j4+0], h4.x, a0);                                       \
        a1 = fmaf(w[4*j4+1], h4.y, a1);                                       \
        a2 = fmaf(w[4*j4+2], h4.z, a2);                                       \
        a3 = fmaf(w[4*j4+3], h4.w, a3);                                       \
    }                                                                         \
    HQ = fmaxf((a0 + a1) + (a2 + a3), 0.0f);                                  \
    hsh[NXTBUF][lane] = HQ;                                                   \
}

template<int DIR>
__device__ __noinline__ void rnn_serial(const float* __restrict__ W,
                                        float* __restrict__ xh,
                                        int b, int lane)
{
    float w[HH];
    {
        const float4* wp = (const float4*)(W + lane * HH);
        #pragma unroll
        for (int j4 = 0; j4 < HH / 4; ++j4) {
            float4 v = wp[j4];
            w[4*j4+0] = v.x; w[4*j4+1] = v.y; w[4*j4+2] = v.z; w[4*j4+3] = v.w;
        }
    }
    float* base = xh + ((size_t)(DIR * BB + b) * HH + lane) * TT;

    __shared__ __align__(16) float hsh[2][HH];
    hsh[0][lane] = 0.0f;
    __syncthreads();

    constexpr int STEP = DIR ? -4 : 4;
    int gbase = DIR ? (TT - 4) : 0;
    float4 xq = *(const float4*)(base + gbase);

    for (int g = 0; g < TT / 4; ++g) {
        const int gnext = (g + 1 < TT / 4) ? (gbase + STEP) : gbase;
        const float4 xn = *(const float4*)(base + gnext);

        float hq0, hq1, hq2, hq3;
        if (DIR == 0) {
            RNN_STEP(xq.x, hq0, 0, 1)
            RNN_STEP(xq.y, hq1, 1, 0)
            RNN_STEP(xq.z, hq2, 0, 1)
            RNN_STEP(xq.w, hq3, 1, 0)
        } else {
            RNN_STEP(xq.w, hq0, 0, 1)
            RNN_STEP(xq.z, hq1, 1, 0)
            RNN_STEP(xq.y, hq2, 0, 1)
            RNN_STEP(xq.x, hq3, 1, 0)
        }

        float4 st;
        if (DIR == 0) { st.x = hq0; st.y = hq1; st.z = hq2; st.w = hq3; }
        else          { st.x = hq3; st.y = hq2; st.z = hq1; st.w = hq0; }
        *(float4*)(base + gbase) = st;

        gbase = gnext;
        xq = xn;
    }
}

// ---------------- rnn: identity fast-path (parallel scan) + fallback ----------
// h_t = max(h_{t-1} + a_t, 0) is f(h)=max(h+a,b) with b=0; composition
// (A,B) then (A',B') = (A+A', max(B+A', B')) is associative -> prefix scan.
__global__ __launch_bounds__(64) void rnn_kernel(
    const float* __restrict__ Whf, const float* __restrict__ Whb,
    float* __restrict__ xh)
{
    const int lane = threadIdx.x;
    const int row  = blockIdx.x;         // 0..16383
    const int dir  = row >> 13;
    const int rid  = row & 8191;
    const int b    = rid >> 6;
    const int hrow = rid & 63;
    const float* W = dir ? Whb : Whf;

    // load W row `lane` and test identity (wave-uniform verdict)
    bool ok = true;
    {
        const float4* wp = (const float4*)(W + lane * HH);
        #pragma unroll
        for (int j4 = 0; j4 < HH / 4; ++j4) {
            float4 v = wp[j4];
            ok &= (v.x == ((4*j4+0 == lane) ? 1.0f : 0.0f));
            ok &= (v.y == ((4*j4+1 == lane) ? 1.0f : 0.0f));
            ok &= (v.z == ((4*j4+2 == lane) ? 1.0f : 0.0f));
            ok &= (v.w == ((4*j4+3 == lane) ? 1.0f : 0.0f));
        }
    }
    const bool isI = (__ballot(ok) == ~0ull);

    if (!isI) {
        if (hrow != 0) return;
        if (dir == 0) rnn_serial<0>(Whf, xh, b, lane);
        else          rnn_serial<1>(Whb, xh, b, lane);
        return;
    }

    float* base = xh + ((size_t)(dir * BB + b) * HH + hrow) * TT;

    // gather this lane's 32 elements in TIME order (dir=1: memory-reversed)
    float a[32];
    if (dir == 0) {
        const float4* xp = (const float4*)(base + lane * 32);
        #pragma unroll
        for (int q = 0; q < 8; ++q) {
            float4 v = xp[q];
            a[4*q+0] = v.x; a[4*q+1] = v.y; a[4*q+2] = v.z; a[4*q+3] = v.w;
        }
    } else {
        const float4* xp = (const float4*)(base + (TT - 32 - lane * 32));
        #pragma unroll
        for (int q = 0; q < 8; ++q) {
            float4 v = xp[q];
            a[31-4*q] = v.x; a[30-4*q] = v.y; a[29-4*q] = v.z; a[28-4*q] = v.w;
        }
    }

    // in-lane compose over 32 elems: (A,B) with identity (0, -inf)
    float A = 0.0f, Bv = -__builtin_inff();
    #pragma unroll
    for (int j = 0; j < 32; ++j) {
        A  = A + a[j];
        Bv = fmaxf(Bv + a[j], 0.0f);
    }

    // inclusive wave scan over lanes
    #pragma unroll
    for (int off = 1; off < 64; off <<= 1) {
        float Au = __shfl_up(A,  (unsigned)off);
        float Bu = __shfl_up(Bv, (unsigned)off);
        if (lane >= off) {
            Bv = fmaxf(Bu + A, Bv);   // uses pre-update A (current segment's A)
            A  = Au + A;
        }
    }

    // carry-in = exclusive prefix applied to h_init = 0
    float Ae = __shfl_up(A, 1u);
    float Be = __shfl_up(Bv, 1u);
    float h = (lane == 0) ? 0.0f : fmaxf(Ae, Be);

    // apply sequentially within the lane (exact within-segment arithmetic)
    #pragma unroll
    for (int j = 0; j < 32; ++j) {
        h = fmaxf(h + a[j], 0.0f);
        a[j] = h;
    }

    // store back in memory order
    if (dir == 0) {
        float4* op = (float4*)(base + lane * 32);
        #pragma unroll
        for (int q = 0; q < 8; ++q) {
            float4 st; st.x = a[4*q+0]; st.y = a[4*q+1]; st.z = a[4*q+2]; st.w = a[4*q+3];
            op[q] = st;
        }
    } else {
        float4* op = (float4*)(base + (TT - 32 - lane * 32));
        #pragma unroll
        for (int q = 0; q < 8; ++q) {
            float4 st; st.x = a[31-4*q]; st.y = a[30-4*q]; st.z = a[29-4*q]; st.w = a[28-4*q];
            op[q] = st;
        }
    }
}

// ---------------- mlp: k-tiled, NAMED-SCALAR accumulators (no alloca) --------
// R3/R4 post-mortem: hr[128] local array was never SROA-promoted (constant
// indices only appear after unroll) -> lived in scratch -> 6x slowdown at
// VGPR_Count=88 regardless of __launch_bounds__. This version has no indexed
// local arrays at all: 16 named accumulators per k-tile, h streamed from
// global (L1/L2-hit after first tile), w0 rows wave-uniform (scalar-cached).
#define REP16(M) M(0) M(1) M(2) M(3) M(4) M(5) M(6) M(7) \
                 M(8) M(9) M(10) M(11) M(12) M(13) M(14) M(15)

__global__ __launch_bounds__(256, 2) void mlp_kernel(
    const float* __restrict__ xh,
    const float* __restrict__ w0, const float* __restrict__ b0,
    const float* __restrict__ w1, const float* __restrict__ b1,
    float* __restrict__ out)
{
    const int lane = threadIdx.x & 63;
    const int tile = __builtin_amdgcn_readfirstlane(blockIdx.x * 4 + (threadIdx.x >> 6));
    const int b = tile >> 5;
    const int t = ((tile & 31) << 6) + lane;

    const float* pf = xh + (size_t)b * HH * TT + t;        // forward h, stride TT per j
    const float* pb = xh + (size_t)(BB + b) * HH * TT + t; // backward h

    float oa = 0.0f;

    #pragma unroll 1
    for (int kt = 0; kt < 8; ++kt) {
        const float* wk = w0 + kt * 16 * 128;   // rows k = kt*16 .. kt*16+15

        #define DC(i) float c##i = b0[kt * 16 + i];
        REP16(DC)
        #undef DC

        // j = 0..63  (forward half)
        #pragma unroll 1
        for (int j4 = 0; j4 < 16; ++j4) {
            const float hA = pf[(size_t)(4 * j4 + 0) * TT];
            const float hB = pf[(size_t)(4 * j4 + 1) * TT];
            const float hC = pf[(size_t)(4 * j4 + 2) * TT];
            const float hD = pf[(size_t)(4 * j4 + 3) * TT];
            const float* wbase = wk + 4 * j4;            // wave-uniform
            #define WF(i) { float4 wq = *(const float4*)(wbase + i * 128); \
                            c##i = fmaf(wq.x, hA, c##i);                   \
                            c##i = fmaf(wq.y, hB, c##i);                   \
                            c##i = fmaf(wq.z, hC, c##i);                   \
                            c##i = fmaf(wq.w, hD, c##i); }
            REP16(WF)
            #undef WF
        }

        // j = 64..127  (backward half)
        #pragma unroll 1
        for (int j4 = 0; j4 < 16; ++j4) {
            const float hA = pb[(size_t)(4 * j4 + 0) * TT];
            const float hB = pb[(size_t)(4 * j4 + 1) * TT];
            const float hC = pb[(size_t)(4 * j4 + 2) * TT];
            const float hD = pb[(size_t)(4 * j4 + 3) * TT];
            const float* wbase = wk + 64 + 4 * j4;       // wave-uniform
            #define WF(i) { float4 wq = *(const float4*)(wbase + i * 128); \
                            c##i = fmaf(wq.x, hA, c##i);                   \
                            c##i = fmaf(wq.y, hB, c##i);                   \
                            c##i = fmaf(wq.z, hC, c##i);                   \
                            c##i = fmaf(wq.w, hD, c##i); }
            REP16(WF)
            #undef WF
        }

        // leaky_relu + second layer, k order preserved
        #define EP(i) { float v = fmaxf(c##i, 0.01f * c##i); \
                        oa = fmaf(v, w1[kt * 16 + i], oa); }
        REP16(EP)
        #undef EP
    }

    out[(size_t)b * TT + t] = oa + b1[0];
}

extern "C" void kernel_launch(void* const* d_in, const int* in_sizes, int n_in,
                              void* d_out, int out_size, void* d_ws, size_t ws_size,
                              hipStream_t stream) {
    (void)in_sizes; (void)n_in; (void)out_size; (void)ws_size;
    const float* x    = (const float*)d_in[0];
    const float* Wihf = (const float*)d_in[1];
    const float* Whhf = (const float*)d_in[2];
    const float* bihf = (const float*)d_in[3];
    const float* bhhf = (const float*)d_in[4];
    const float* Wihb = (const float*)d_in[5];
    const float* Whhb = (const float*)d_in[6];
    const float* bihb = (const float*)d_in[7];
    const float* bhhb = (const float*)d_in[8];
    const float* ff0w = (const float*)d_in[9];
    const float* ff0b = (const float*)d_in[10];
    const float* ff1w = (const float*)d_in[11];
    const float* ff1b = (const float*)d_in[12];
    float* xh = (float*)d_ws;

    proj_kernel<<<dim3(BB * (TT / 64)), dim3(256), 0, stream>>>(
        x, Wihf, bihf, bhhf, Wihb, bihb, bhhb, xh);
    rnn_kernel<<<dim3(2 * BB * HH), dim3(64), 0, stream>>>(Whhf, Whhb, xh);
    mlp_kernel<<<dim3(BB * (TT / 64) / 4), dim3(256), 0, stream>>>(
        xh, ff0w, ff0b, ff1w, ff1b, (float*)d_out);
}